// Round 3
// baseline (600.528 us; speedup 1.0000x reference)
//
#include <hip/hip_runtime.h>
#include <math.h>

#define TOKENS 8192
#define DIM 4096
#define NEXP 256
#define TK 8
#define ROUTE_SCALE 2.5f

#define BM 64
#define BN 64
#define BK 32
#define PITCH 68   // floats per [k] row: 64 + 4 pad; 68*4=272 B = 17*16 -> b128-aligned rows

// ---------------------------------------------------------------------------
// Kernel 1: scores = sigmoid(x @ W^T), fp32 VALU.
// BIT-IDENTICAL accumulation to the round-1 passing kernel: each output's
// FMA chain is strictly k-serial (k = 0..4095 in order, explicit fmaf).
// 128 thr/block, BM=BN=64, BK=32, 8x4 register tile, register-prefetch
// double buffering of the global tile. Grid 512 = 2 blocks/CU.
// ---------------------------------------------------------------------------
__global__ __launch_bounds__(128) void score_gemm(const float* __restrict__ x,
                                                  const float* __restrict__ W,
                                                  float* __restrict__ scores) {
    __shared__ __align__(16) float As[BK][PITCH];   // [k][m]
    __shared__ __align__(16) float Bs[BK][PITCH];   // [k][e]

    const int m0 = blockIdx.x * BM;
    const int e0 = blockIdx.y * BN;
    const int tid = threadIdx.x;

    // staging: thread owns rows {sr+16i}, k-cols sc..sc+3 of the 64x32 tile
    const int sr = tid >> 3;          // 0..15
    const int sc = (tid & 7) << 2;    // 0,4,..,28
    // compute: 8 token-rows (ty*8..+7), 4 expert-cols (tx*4..+3)
    const int tx = tid & 15;          // 0..15
    const int ty = tid >> 4;          // 0..7

    const float* xa = x + (size_t)(m0 + sr) * DIM + sc;
    const float* wa = W + (size_t)(e0 + sr) * DIM + sc;

    float acc[8][4];
#pragma unroll
    for (int i = 0; i < 8; i++)
#pragma unroll
        for (int j = 0; j < 4; j++) acc[i][j] = 0.0f;

    float4 sa[4], sb[4];
#pragma unroll
    for (int i = 0; i < 4; i++) {
        sa[i] = *(const float4*)(xa + (size_t)(16 * i) * DIM);
        sb[i] = *(const float4*)(wa + (size_t)(16 * i) * DIM);
    }

#pragma unroll 1
    for (int kt = 0; kt < DIM / BK; ++kt) {
        __syncthreads();   // all waves done reading LDS from previous ktile
#pragma unroll
        for (int i = 0; i < 4; i++) {
            const int row = sr + 16 * i;
            As[sc + 0][row] = sa[i].x; As[sc + 1][row] = sa[i].y;
            As[sc + 2][row] = sa[i].z; As[sc + 3][row] = sa[i].w;
            Bs[sc + 0][row] = sb[i].x; Bs[sc + 1][row] = sb[i].y;
            Bs[sc + 2][row] = sb[i].z; Bs[sc + 3][row] = sb[i].w;
        }
        __syncthreads();

        // prefetch next global tile into regs; in flight during compute below
        if (kt + 1 < DIM / BK) {
            const float* xn = xa + (size_t)(kt + 1) * BK;
            const float* wn = wa + (size_t)(kt + 1) * BK;
#pragma unroll
            for (int i = 0; i < 4; i++) {
                sa[i] = *(const float4*)(xn + (size_t)(16 * i) * DIM);
                sb[i] = *(const float4*)(wn + (size_t)(16 * i) * DIM);
            }
        }

#pragma unroll
        for (int k = 0; k < BK; k++) {
            float4 a0 = *(const float4*)&As[k][ty * 8];
            float4 a1 = *(const float4*)&As[k][ty * 8 + 4];
            float4 b0 = *(const float4*)&Bs[k][tx * 4];
            float a_[8] = {a0.x, a0.y, a0.z, a0.w, a1.x, a1.y, a1.z, a1.w};
            float b_[4] = {b0.x, b0.y, b0.z, b0.w};
#pragma unroll
            for (int i = 0; i < 8; i++)
#pragma unroll
                for (int j = 0; j < 4; j++)
                    acc[i][j] = fmaf(a_[i], b_[j], acc[i][j]);
        }
    }

#pragma unroll
    for (int i = 0; i < 8; i++) {
        float4 o;
        o.x = 1.0f / (1.0f + expf(-acc[i][0]));
        o.y = 1.0f / (1.0f + expf(-acc[i][1]));
        o.z = 1.0f / (1.0f + expf(-acc[i][2]));
        o.w = 1.0f / (1.0f + expf(-acc[i][3]));
        *(float4*)&scores[(size_t)(m0 + ty * 8 + i) * NEXP + e0 + tx * 4] = o;
    }
}

// ---------------------------------------------------------------------------
// Kernel 2: routing. 4 tokens per 256-thr block; one wave per token.
// Same algorithm that passed in round 1 (1 token/block there).
// ---------------------------------------------------------------------------
__global__ __launch_bounds__(256) void route_kernel(const float* __restrict__ scores,
                                                    const float* __restrict__ bias,
                                                    float* __restrict__ out_w,
                                                    float* __restrict__ out_i) {
    const int t = blockIdx.x * 4 + (threadIdx.x >> 6);
    const int l = threadIdx.x & 63;

    float4 sc4 = *(const float4*)&scores[(size_t)t * NEXP + (l << 2)];
    float4 b4 = *(const float4*)&bias[l << 2];
    float sc[4] = {sc4.x, sc4.y, sc4.z, sc4.w};
    float sb[4] = {sc4.x + b4.x, sc4.y + b4.y, sc4.z + b4.z, sc4.w + b4.w};

    // local top-2 of 4 biased values
    float hi1 = fmaxf(sb[0], sb[1]), lo1 = fminf(sb[0], sb[1]);
    float hi2 = fmaxf(sb[2], sb[3]), lo2 = fminf(sb[2], sb[3]);
    float m1 = fmaxf(hi1, hi2);
    float m2 = fmaxf(fminf(hi1, hi2), fmaxf(lo1, lo2));

    // merge top-2 across the 8 lanes of the group (xor 1,2,4 stays in-group)
#pragma unroll
    for (int m = 1; m < 8; m <<= 1) {
        float o1 = __shfl_xor(m1, m, 64);
        float o2 = __shfl_xor(m2, m, 64);
        float nm1 = fmaxf(m1, o1);
        float nm2 = fmaxf(fminf(m1, o1), fmaxf(m2, o2));
        m1 = nm1; m2 = nm2;
    }
    float gscore = m1 + m2;

    float gs[8];
#pragma unroll
    for (int g = 0; g < 8; g++) gs[g] = __shfl(gscore, g << 3, 64);

    const int mygrp = l >> 3;
    int rank = 0;
#pragma unroll
    for (int g = 0; g < 8; g++) {
        bool better = (gs[g] > gscore) || (gs[g] == gscore && g < mygrp);
        rank += (g != mygrp && better) ? 1 : 0;
    }
    const bool sel = rank < 4;

    float cand[4];
#pragma unroll
    for (int c = 0; c < 4; c++) cand[c] = sel ? sb[c] : 0.0f;

    // serial top-8: wave argmax, lower-index tie-break (matches lax.top_k)
    float w[8], widx[8];
    float wsum = 0.0f;
#pragma unroll
    for (int r = 0; r < 8; r++) {
        float v = cand[0];
        int idx = (l << 2);
#pragma unroll
        for (int c = 1; c < 4; c++) {
            if (cand[c] > v) { v = cand[c]; idx = (l << 2) + c; }
        }
#pragma unroll
        for (int m = 32; m >= 1; m >>= 1) {
            float ov = __shfl_xor(v, m, 64);
            int oi = __shfl_xor(idx, m, 64);
            if (ov > v || (ov == v && oi < idx)) { v = ov; idx = oi; }
        }
        const int cc = idx & 3;
        const bool own = (idx >> 2) == l;
        cand[0] = (own && cc == 0) ? -__builtin_inff() : cand[0];
        cand[1] = (own && cc == 1) ? -__builtin_inff() : cand[1];
        cand[2] = (own && cc == 2) ? -__builtin_inff() : cand[2];
        cand[3] = (own && cc == 3) ? -__builtin_inff() : cand[3];
        float tmp = (cc == 0) ? sc[0] : (cc == 1) ? sc[1] : (cc == 2) ? sc[2] : sc[3];
        float ws = __shfl(tmp, idx >> 2, 64);
        w[r] = ws;
        widx[r] = (float)idx;
        wsum += ws;
    }

    const float scale = ROUTE_SCALE / wsum;
    if (l == 0) {
        float* ow = out_w + (size_t)t * TK;
        float* oi = out_i + (size_t)t * TK;
#pragma unroll
        for (int r = 0; r < 8; r++) ow[r] = w[r] * scale;
#pragma unroll
        for (int r = 0; r < 8; r++) oi[r] = widx[r];
    }
}

extern "C" void kernel_launch(void* const* d_in, const int* in_sizes, int n_in,
                              void* d_out, int out_size, void* d_ws, size_t ws_size,
                              hipStream_t stream) {
    const float* x = (const float*)d_in[0];
    const float* W = (const float*)d_in[1];
    const float* bias = (const float*)d_in[2];
    float* out = (float*)d_out;
    float* scores = (float*)d_ws;            // 8192*256 f32 = 8 MB scratch

    dim3 gGemm(TOKENS / BM, NEXP / BN);      // 128 x 4 = 512 blocks, 2/CU
    score_gemm<<<gGemm, 128, 0, stream>>>(x, W, scores);

    route_kernel<<<TOKENS / 4, 256, 0, stream>>>(scores, bias, out, out + (size_t)TOKENS * TK);
}

// Round 4
// 427.756 us; speedup vs baseline: 1.4039x; 1.4039x over previous
//
#include <hip/hip_runtime.h>
#include <math.h>

#define TOKENS 8192
#define DIM 4096
#define NEXP 256
#define TK 8
#define ROUTE_SCALE 2.5f
#define MARGIN 4e-6f   // >=10x the worst-case f16-split score error (~3e-7)

#define BM 128
#define BN 64
#define BK 64
#define PITCH 72   // halfs per LDS row: 144 B, 16B-aligned, breaks pow2 banks

typedef _Float16 half8 __attribute__((ext_vector_type(8)));
typedef _Float16 half4v __attribute__((ext_vector_type(4)));
typedef float f4 __attribute__((ext_vector_type(4)));

union H8 { half8 v; int4 q; };

// ---------------------------------------------------------------------------
// Pre-kernel: W -> (W*256) split into f16 hi + f16 lo*2048. Scaling keeps all
// stored values in f16 normal range (no MFMA denorm-flush exposure).
// ---------------------------------------------------------------------------
__global__ __launch_bounds__(256) void wsplit(const float* __restrict__ W,
                                              _Float16* __restrict__ Wh,
                                              _Float16* __restrict__ Wl) {
    int i = blockIdx.x * 256 + threadIdx.x;        // float4 index
    float4 w = ((const float4*)W)[i];
    const float* wf = (const float*)&w;
    half4v h, l;
#pragma unroll
    for (int j = 0; j < 4; j++) {
        float ws = wf[j] * 256.0f;                 // exact (pow2)
        _Float16 hj = (_Float16)ws;                // RNE
        float r = ws - (float)hj;                  // exact residual
        h[j] = hj;
        l[j] = (_Float16)(r * 2048.0f);            // scaled into normal range
    }
    *(half4v*)(Wh + 4 * (size_t)i) = h;
    *(half4v*)(Wl + 4 * (size_t)i) = l;
}

// ---------------------------------------------------------------------------
// Kernel 1: logits = x @ W^T via 3-term f16-split MFMA; scores = sigmoid.
// BM=128 BN=64 BK=64, 256 thr (4 waves, 2x2 wave grid, wave tile 64x32).
// A: fp32 global -> regs (prefetched) -> split x*16 -> LDS. B: direct global.
// logit = (accH + accC/2048) / 4096   (x scaled 16, W scaled 256)
// ---------------------------------------------------------------------------
__global__ __launch_bounds__(256, 1) void score_gemm(const float* __restrict__ x,
                                                     const _Float16* __restrict__ Wh,
                                                     const _Float16* __restrict__ Wl,
                                                     float* __restrict__ scores) {
    __shared__ __align__(16) _Float16 sAh[BM * PITCH];
    __shared__ __align__(16) _Float16 sAl[BM * PITCH];

    const int m0 = blockIdx.x * BM;
    const int e0 = blockIdx.y * BN;
    const int tid = threadIdx.x;
    const int lane = tid & 63;
    const int wave = tid >> 6;
    const int wm = (wave >> 1) * 64;
    const int wn = (wave & 1) * 32;

    // A staging: thread owns rows {ar+32i}, cols ac..ac+7 of the 128x64 tile
    const int ar = tid >> 3;
    const int ac = (tid & 7) * 8;
    const float* xa = x + (size_t)(m0 + ar) * DIM + ac;

    // B fragment: lane holds B[k=8*(lane>>4)+j][n=lane&15] = W[e0+wn+n][k]
    const int b_row = e0 + wn + (lane & 15);
    const int b_k = (lane >> 4) * 8;

    f4 accH[4][2], accC[4][2];
#pragma unroll
    for (int i = 0; i < 4; i++)
#pragma unroll
        for (int j = 0; j < 2; j++) { accH[i][j] = (f4)0.0f; accC[i][j] = (f4)0.0f; }

    float4 sa[8];
#pragma unroll
    for (int i = 0; i < 4; i++) {
        sa[2 * i] = *(const float4*)(xa + (size_t)(32 * i) * DIM);
        sa[2 * i + 1] = *(const float4*)(xa + (size_t)(32 * i) * DIM + 4);
    }

    for (int kt = 0; kt < DIM / BK; ++kt) {
        // B frags for this ktile (global/L2; in flight during convert phase)
        half8 bh[2][2], bl[2][2];
#pragma unroll
        for (int s = 0; s < 2; s++)
#pragma unroll
            for (int nt = 0; nt < 2; nt++) {
                size_t off = (size_t)(b_row + nt * 16) * DIM + kt * BK + s * 32 + b_k;
                bh[s][nt] = *(const half8*)(Wh + off);
                bl[s][nt] = *(const half8*)(Wl + off);
            }

        __syncthreads();   // all waves done reading LDS from previous ktile
#pragma unroll
        for (int i = 0; i < 4; i++) {
            const float* f0 = (const float*)&sa[2 * i];
            const float* f1 = (const float*)&sa[2 * i + 1];
            H8 hh, hl;
#pragma unroll
            for (int j = 0; j < 8; j++) {
                float xv = (j < 4 ? f0[j] : f1[j - 4]) * 16.0f;   // exact (pow2)
                _Float16 h = (_Float16)xv;                         // RNE
                float r = xv - (float)h;                           // exact
                hh.v[j] = h;
                hl.v[j] = (_Float16)(r * 2048.0f);
            }
            const int row = ar + 32 * i;
            *(int4*)&sAh[row * PITCH + ac] = hh.q;
            *(int4*)&sAl[row * PITCH + ac] = hl.q;
        }
        __syncthreads();

        // prefetch next A ktile into regs (overlaps MFMA phase)
        if (kt + 1 < DIM / BK) {
            const float* xn = xa + (size_t)(kt + 1) * BK;
#pragma unroll
            for (int i = 0; i < 4; i++) {
                sa[2 * i] = *(const float4*)(xn + (size_t)(32 * i) * DIM);
                sa[2 * i + 1] = *(const float4*)(xn + (size_t)(32 * i) * DIM + 4);
            }
        }

#pragma unroll
        for (int s = 0; s < 2; s++) {
            half8 ah[4], al[4];
#pragma unroll
            for (int mt = 0; mt < 4; mt++) {
                int row = wm + mt * 16 + (lane & 15);
                int col = s * 32 + (lane >> 4) * 8;
                ah[mt] = *(const half8*)&sAh[row * PITCH + col];
                al[mt] = *(const half8*)&sAl[row * PITCH + col];
            }
#pragma unroll
            for (int mt = 0; mt < 4; mt++)
#pragma unroll
                for (int nt = 0; nt < 2; nt++) {
                    accH[mt][nt] = __builtin_amdgcn_mfma_f32_16x16x32_f16(ah[mt], bh[s][nt], accH[mt][nt], 0, 0, 0);
                    accC[mt][nt] = __builtin_amdgcn_mfma_f32_16x16x32_f16(ah[mt], bl[s][nt], accC[mt][nt], 0, 0, 0);
                    accC[mt][nt] = __builtin_amdgcn_mfma_f32_16x16x32_f16(al[mt], bh[s][nt], accC[mt][nt], 0, 0, 0);
                }
        }
    }

    // epilogue: recombine, sigmoid, store. C layout: col=lane&15, row=quad*4+r
#pragma unroll
    for (int mt = 0; mt < 4; mt++)
#pragma unroll
        for (int nt = 0; nt < 2; nt++) {
            int m = m0 + wm + mt * 16 + ((lane >> 4) << 2);
            int e = e0 + wn + nt * 16 + (lane & 15);
#pragma unroll
            for (int r = 0; r < 4; r++) {
                float v = (accH[mt][nt][r] + accC[mt][nt][r] * (1.0f / 2048.0f)) * (1.0f / 4096.0f);
                scores[(size_t)(m + r) * NEXP + e] = 1.0f / (1.0f + expf(-v));
            }
        }
}

// ---------------------------------------------------------------------------
// Kernel 2: routing + margin flagging. 4 tokens / 256-thr block, 1 wave/token.
// ---------------------------------------------------------------------------
__global__ __launch_bounds__(256) void route_kernel(const float* __restrict__ scores,
                                                    const float* __restrict__ bias,
                                                    float* __restrict__ out_w,
                                                    float* __restrict__ out_i,
                                                    int* __restrict__ flag_cnt,
                                                    int* __restrict__ flag_list) {
    const int t = blockIdx.x * 4 + (threadIdx.x >> 6);
    const int l = threadIdx.x & 63;

    float4 sc4 = *(const float4*)&scores[(size_t)t * NEXP + (l << 2)];
    float4 b4 = *(const float4*)&bias[l << 2];
    float sc[4] = {sc4.x, sc4.y, sc4.z, sc4.w};
    float sb[4] = {sc4.x + b4.x, sc4.y + b4.y, sc4.z + b4.z, sc4.w + b4.w};

    // per-lane top-3 of its 4 biased values
    float h1 = fmaxf(sb[0], sb[1]), q1 = fminf(sb[0], sb[1]);
    float h2 = fmaxf(sb[2], sb[3]), q2 = fminf(sb[2], sb[3]);
    float m1 = fmaxf(h1, h2);
    float shi = fminf(h1, h2), hlo = fmaxf(q1, q2);
    float m2 = fmaxf(shi, hlo);
    float m3 = fminf(shi, hlo);

    // butterfly top-3 merge across the 8 lanes of the group
#pragma unroll
    for (int m = 1; m < 8; m <<= 1) {
        float o1 = __shfl_xor(m1, m, 64);
        float o2 = __shfl_xor(m2, m, 64);
        float o3 = __shfl_xor(m3, m, 64);
        bool aw = (m1 >= o1);
        float A1 = aw ? m1 : o1, A2 = aw ? m2 : o2, A3 = aw ? m3 : o3;
        float B1 = aw ? o1 : m1, B2 = aw ? o2 : m2;
        float v2, v3;
        if (A2 >= B1) { v2 = A2; v3 = fmaxf(B1, A3); }
        else          { v2 = B1; v3 = fmaxf(A2, B2); }
        m1 = A1; m2 = v2; m3 = v3;
    }
    float gscore = m1 + m2;
    float gap23 = m2 - m3;                 // within-group top2 vs top3
#pragma unroll
    for (int m = 8; m < 64; m <<= 1) gap23 = fminf(gap23, __shfl_xor(gap23, m, 64));

    float gs[8];
#pragma unroll
    for (int g = 0; g < 8; g++) gs[g] = __shfl(gscore, g << 3, 64);

    const int mygrp = l >> 3;
    int rank = 0;
#pragma unroll
    for (int g = 0; g < 8; g++) {
        bool better = (gs[g] > gscore) || (gs[g] == gscore && g < mygrp);
        rank += (g != mygrp && better) ? 1 : 0;
    }
    const bool sel = rank < 4;

    // group-selection boundary gap (4th vs 5th group score)
    float minsel = 1e30f, maxuns = -1e30f;
#pragma unroll
    for (int g = 0; g < 8; g++) {
        int rg = 0;
#pragma unroll
        for (int g2 = 0; g2 < 8; g2++)
            rg += (g2 != g && ((gs[g2] > gs[g]) || (gs[g2] == gs[g] && g2 < g))) ? 1 : 0;
        if (rg < 4) minsel = fminf(minsel, gs[g]); else maxuns = fmaxf(maxuns, gs[g]);
    }
    float gap45 = minsel - maxuns;

    float cand[4];
#pragma unroll
    for (int c = 0; c < 4; c++) cand[c] = sel ? sb[c] : 0.0f;

    // serial top-9 extraction (9th only for the boundary gap)
    float wv[8], wi[8], vb[9];
    float wsum = 0.0f;
#pragma unroll
    for (int r = 0; r < 9; r++) {
        float v = cand[0];
        int idx = (l << 2);
#pragma unroll
        for (int c = 1; c < 4; c++) {
            if (cand[c] > v) { v = cand[c]; idx = (l << 2) + c; }
        }
#pragma unroll
        for (int m = 32; m >= 1; m >>= 1) {
            float ov = __shfl_xor(v, m, 64);
            int oi = __shfl_xor(idx, m, 64);
            if (ov > v || (ov == v && oi < idx)) { v = ov; idx = oi; }
        }
        vb[r] = v;
        if (r < 8) {
            const int cc = idx & 3;
            const bool own = (idx >> 2) == l;
            cand[0] = (own && cc == 0) ? -__builtin_inff() : cand[0];
            cand[1] = (own && cc == 1) ? -__builtin_inff() : cand[1];
            cand[2] = (own && cc == 2) ? -__builtin_inff() : cand[2];
            cand[3] = (own && cc == 3) ? -__builtin_inff() : cand[3];
            float tmp = (cc == 0) ? sc[0] : (cc == 1) ? sc[1] : (cc == 2) ? sc[2] : sc[3];
            float ws = __shfl(tmp, idx >> 2, 64);
            wv[r] = ws;
            wi[r] = (float)idx;
            wsum += ws;
        }
    }
    float mingap = 1e30f;
#pragma unroll
    for (int r = 0; r < 8; r++) mingap = fminf(mingap, vb[r] - vb[r + 1]);

    const float scale = ROUTE_SCALE / wsum;
    if (l == 0) {
        float* ow = out_w + (size_t)t * TK;
        float* oi = out_i + (size_t)t * TK;
#pragma unroll
        for (int r = 0; r < 8; r++) ow[r] = wv[r] * scale;
#pragma unroll
        for (int r = 0; r < 8; r++) oi[r] = wi[r];
        if (gap23 < MARGIN || gap45 < MARGIN || mingap < MARGIN) {
            int pos = atomicAdd(flag_cnt, 1);
            flag_list[pos] = t;
        }
    }
}

// ---------------------------------------------------------------------------
// Kernel 3: fixup. For flagged tokens recompute all 256 logits with the
// bit-identical serial fp32 fmaf chain (== round-1 passing kernel) + re-route.
// ---------------------------------------------------------------------------
__global__ __launch_bounds__(256) void fixup_kernel(const float* __restrict__ x,
                                                    const float* __restrict__ W,
                                                    const float* __restrict__ bias,
                                                    const int* __restrict__ flag_cnt,
                                                    const int* __restrict__ flag_list,
                                                    float* __restrict__ out_w,
                                                    float* __restrict__ out_i) {
    __shared__ float S[NEXP];
    const int n = *flag_cnt;
    for (int i = blockIdx.x; i < n; i += gridDim.x) {
        const int t = flag_list[i];
        const float* xr = x + (size_t)t * DIM;
        const float* wr = W + (size_t)threadIdx.x * DIM;
        float acc = 0.0f;
        for (int k = 0; k < DIM; k += 4) {           // strictly k-serial fmaf chain
            float4 xv = *(const float4*)(xr + k);
            float4 wv = *(const float4*)(wr + k);
            acc = fmaf(xv.x, wv.x, acc);
            acc = fmaf(xv.y, wv.y, acc);
            acc = fmaf(xv.z, wv.z, acc);
            acc = fmaf(xv.w, wv.w, acc);
        }
        S[threadIdx.x] = 1.0f / (1.0f + expf(-acc));
        __syncthreads();
        if (threadIdx.x < 64) {
            const int l = threadIdx.x;
            float sc[4] = {S[4 * l], S[4 * l + 1], S[4 * l + 2], S[4 * l + 3]};
            float4 b4 = *(const float4*)&bias[4 * l];
            float sb[4] = {sc[0] + b4.x, sc[1] + b4.y, sc[2] + b4.z, sc[3] + b4.w};

            float h1 = fmaxf(sb[0], sb[1]), q1 = fminf(sb[0], sb[1]);
            float h2 = fmaxf(sb[2], sb[3]), q2 = fminf(sb[2], sb[3]);
            float m1 = fmaxf(h1, h2);
            float m2 = fmaxf(fminf(h1, h2), fmaxf(q1, q2));
#pragma unroll
            for (int m = 1; m < 8; m <<= 1) {
                float o1 = __shfl_xor(m1, m, 64);
                float o2 = __shfl_xor(m2, m, 64);
                float nm1 = fmaxf(m1, o1);
                float nm2 = fmaxf(fminf(m1, o1), fmaxf(m2, o2));
                m1 = nm1; m2 = nm2;
            }
            float gscore = m1 + m2;
            float gs[8];
#pragma unroll
            for (int g = 0; g < 8; g++) gs[g] = __shfl(gscore, g << 3, 64);
            const int mygrp = l >> 3;
            int rank = 0;
#pragma unroll
            for (int g = 0; g < 8; g++) {
                bool better = (gs[g] > gscore) || (gs[g] == gscore && g < mygrp);
                rank += (g != mygrp && better) ? 1 : 0;
            }
            const bool selg = rank < 4;
            float cand[4];
#pragma unroll
            for (int c = 0; c < 4; c++) cand[c] = selg ? sb[c] : 0.0f;
            float wv[8], wi[8];
            float wsum = 0.0f;
#pragma unroll
            for (int r = 0; r < 8; r++) {
                float v = cand[0];
                int idx = (l << 2);
#pragma unroll
                for (int c = 1; c < 4; c++) {
                    if (cand[c] > v) { v = cand[c]; idx = (l << 2) + c; }
                }
#pragma unroll
                for (int m = 32; m >= 1; m >>= 1) {
                    float ov = __shfl_xor(v, m, 64);
                    int oi = __shfl_xor(idx, m, 64);
                    if (ov > v || (ov == v && oi < idx)) { v = ov; idx = oi; }
                }
                const int cc = idx & 3;
                const bool own = (idx >> 2) == l;
                cand[0] = (own && cc == 0) ? -__builtin_inff() : cand[0];
                cand[1] = (own && cc == 1) ? -__builtin_inff() : cand[1];
                cand[2] = (own && cc == 2) ? -__builtin_inff() : cand[2];
                cand[3] = (own && cc == 3) ? -__builtin_inff() : cand[3];
                float tmp = (cc == 0) ? sc[0] : (cc == 1) ? sc[1] : (cc == 2) ? sc[2] : sc[3];
                float ws = __shfl(tmp, idx >> 2, 64);
                wv[r] = ws;
                wi[r] = (float)idx;
                wsum += ws;
            }
            const float scale = ROUTE_SCALE / wsum;
            if (l == 0) {
                float* ow = out_w + (size_t)t * TK;
                float* oi = out_i + (size_t)t * TK;
#pragma unroll
                for (int r = 0; r < 8; r++) ow[r] = wv[r] * scale;
#pragma unroll
                for (int r = 0; r < 8; r++) oi[r] = wi[r];
            }
        }
        __syncthreads();
    }
}

__global__ void zero_cnt(int* c) { if (threadIdx.x == 0) *c = 0; }

extern "C" void kernel_launch(void* const* d_in, const int* in_sizes, int n_in,
                              void* d_out, int out_size, void* d_ws, size_t ws_size,
                              hipStream_t stream) {
    const float* x = (const float*)d_in[0];
    const float* W = (const float*)d_in[1];
    const float* bias = (const float*)d_in[2];
    float* out = (float*)d_out;

    char* ws = (char*)d_ws;
    float* scores = (float*)ws;                                    // 8 MB
    _Float16* Wh = (_Float16*)(ws + (size_t)TOKENS * NEXP * 4);    // 2 MB
    _Float16* Wl = Wh + (size_t)NEXP * DIM;                        // 2 MB
    int* flag_cnt = (int*)(ws + (size_t)TOKENS * NEXP * 4 + (size_t)NEXP * DIM * 4);
    int* flag_list = flag_cnt + 4;                                 // up to 8192 ints

    zero_cnt<<<1, 64, 0, stream>>>(flag_cnt);
    wsplit<<<NEXP * DIM / 4 / 256, 256, 0, stream>>>(W, Wh, Wl);

    dim3 gGemm(TOKENS / BM, NEXP / BN);   // 64 x 4 = 256 blocks
    score_gemm<<<gGemm, 256, 0, stream>>>(x, Wh, Wl, scores);

    route_kernel<<<TOKENS / 4, 256, 0, stream>>>(scores, bias, out,
                                                 out + (size_t)TOKENS * TK,
                                                 flag_cnt, flag_list);
    fixup_kernel<<<128, 256, 0, stream>>>(x, W, bias, flag_cnt, flag_list,
                                          out, out + (size_t)TOKENS * TK);
}